// Round 10
// baseline (131.889 us; speedup 1.0000x reference)
//
#include <hip/hip_runtime.h>
#include <hip/hip_bf16.h>

// z[b,c,m] = sum_d S[m,c,d] * (x[b,d,m] - mean[d,m])
// B=1024, C=64, M=512. x:(B,C,M) f32, mean:(1,C,M), S:(M,C,C), out f32.
//
// v8b: z = S*x - (S*mu).  Prep kernel: Tt[c][m] = sum_d S[m,c,d]*mu[d,m] (ws).
// Main: 512 thr (8 waves, 2 m/wave -> MT=16), BT=16, NB=4, grid 512 = 2
// blocks/CU. LDS 64KB: x 32KB + one z half (32KB) reused for both c-halves.
// All LDS phases at bank floor; 4 lgkm-only barriers/iter (vmcnt in flight).
// v8b tweak: staging lane map ds8=tid&7 (was (tid>>2)&7) -> quarter-wave
// spans all 8 bank-quads on ds_write_b128 (2-way, free); pure lane perm.

typedef __attribute__((ext_vector_type(8))) short short8;
typedef __attribute__((ext_vector_type(4))) float f32x4;

namespace {
constexpr int Mm = 512, Cc = 64, Bb = 1024;
constexpr int MT = 16, BT = 16, NB = 4;

__device__ __forceinline__ short bfc(float f) {  // f32 -> bf16 (RNE, HW cvt)
  __hip_bfloat16 h = __float2bfloat16(f);
  union { __hip_bfloat16 b; short s; } u;
  u.b = h;
  return u.s;
}
}  // namespace

#define ELEM(V, I) ((I) == 0 ? (V).x : (I) == 1 ? (V).y : (I) == 2 ? (V).z : (V).w)

// ---- kernel 1: Tt[c][m] = sum_d S[m,c,d] * mean[d,m]  (one block per m) ----
__global__ __launch_bounds__(256) void zca_prep(const float* __restrict__ S,
                                                const float* __restrict__ mean,
                                                float* __restrict__ Tt) {
  const int m = blockIdx.x;
  const int tid = threadIdx.x;
  const int c = tid >> 2, dq = tid & 3;
  __shared__ float part[256];
  const float* sp = S + (size_t)m * 4096 + c * 64 + dq * 16;
  float acc = 0.f;
#pragma unroll
  for (int jj = 0; jj < 4; ++jj) {
    const float4 sv = *(const float4*)(sp + jj * 4);
#pragma unroll
    for (int k = 0; k < 4; ++k)
      acc += ELEM(sv, k) * mean[(size_t)(dq * 16 + jj * 4 + k) * Mm + m];
  }
  part[tid] = acc;
  __syncthreads();
  if (tid < 64)
    Tt[(size_t)tid * Mm + m] =
        part[tid * 4] + part[tid * 4 + 1] + part[tid * 4 + 2] + part[tid * 4 + 3];
}

// ---- kernel 2: main ----
__global__ __launch_bounds__(512, 4) void zca_v8(
    const float* __restrict__ x, const float* __restrict__ S,
    const float* __restrict__ Tt, float* __restrict__ out) {
  extern __shared__ unsigned char lds[];
  unsigned char* xl = lds;            // 32 KB bf16 x-tile [row=m*16+b][64 d]
  float* zl = (float*)(lds + 32768);  // 32 KB z half-tile [512 rows][16]

  const int tid = threadIdx.x;
  const int l = tid & 63;
  const int w = __builtin_amdgcn_readfirstlane(tid >> 6);  // 0..7

  // XCD-locality mapping: xcd = id&7 (HW round-robin); 4 m-tiles + 16 b-groups
  const int xcd = blockIdx.x & 7, ord = blockIdx.x >> 3;
  const int m0 = (xcd * 4 + (ord & 3)) * MT;
  const int b0 = (ord >> 2) * (BT * NB);

  // staging coords: thread = (d-chunk ds8, m-quad mq, b) — ds8 in low bits so
  // each quarter-wave spans all 8 bank-quads on the b128 staging writes.
  const int ds8 = tid & 7, mq = (tid >> 3) & 3, bl = tid >> 5;
  // z-read coords
  const int rrow = tid >> 2, mqr = tid & 3;
  const int Qm = mqr ^ ((tid >> 4) & 3);  // m-quad this thread ends up holding
  const int psw = (w >> 2) & 1;           // wave-uniform pair-swap key

  float4 st[8];

#define ISSUE(T)                                                             \
  {                                                                          \
    _Pragma("unroll") for (int j = 0; j < 8; ++j) st[j] =                    \
        *(const float4*)(x + (size_t)((b0 + (T)*BT + bl) * Cc + ds8 * 8 + j) \
                                 * Mm + m0 + mq * 4);                        \
  }

#define STAGE()                                                              \
  {                                                                          \
    _Pragma("unroll") for (int i = 0; i < 4; ++i) {                          \
      short8 v8;                                                             \
      _Pragma("unroll") for (int j = 0; j < 8; ++j) v8[j] =                  \
          bfc(ELEM(st[j], i));                                               \
      *(short8*)(xl + ((mq * 4 + i) * 16 + bl) * 128 +                       \
                 ((ds8 ^ (bl & 7)) << 4)) = v8;                              \
    }                                                                        \
  }

#define BAR()                                          \
  {                                                    \
    asm volatile("s_waitcnt lgkmcnt(0)" ::: "memory"); \
    __builtin_amdgcn_s_barrier();                      \
  }

#define ZW(H)                                                                  \
  {                                                                            \
    _Pragma("unroll") for (int mi = 0; mi < 2; ++mi)                           \
    _Pragma("unroll") for (int cth = 0; cth < 2; ++cth)                        \
    _Pragma("unroll") for (int r = 0; r < 4; ++r) {                            \
      const int mloc = w * 2 + mi, h = l >> 4, bz = l & 15;                    \
      const int zrow = (cth * 16 + h * 4 + r) * 16 + bz;                       \
      const int col =                                                          \
          ((mloc & 3) ^ h) | ((((mloc >> 2) ^ (bz >> 2)) & 3) << 2);           \
      zl[zrow * 16 + col] = acc[mi][(H)*2 + cth][r];                           \
    }                                                                          \
  }

#define ZR(H, T)                                                               \
  {                                                                            \
    _Pragma("unroll") for (int t2 = 0; t2 < 4; ++t2) {                         \
      const int zrow = t2 * 128 + rrow;                                        \
      float4 v = *(const float4*)(zl + zrow * 16 + mqr * 4);                   \
      if (t2 & 1) { /* compile-time half swap */                               \
        float tt = v.x; v.x = v.z; v.z = tt;                                   \
        tt = v.y; v.y = v.w; v.w = tt;                                         \
      }                                                                        \
      if (psw) { /* wave-uniform pair swap */                                  \
        float tt = v.x; v.x = v.y; v.y = tt;                                   \
        tt = v.z; v.z = v.w; v.w = tt;                                         \
      }                                                                        \
      const int cl = (H)*32 + t2 * 8 + w, bz = rrow & 15;                      \
      const float4 tq =                                                        \
          *(const float4*)(Tt + (size_t)cl * Mm + m0 + Qm * 4);                \
      const float4 o =                                                         \
          make_float4(v.x - tq.x, v.y - tq.y, v.z - tq.z, v.w - tq.w);         \
      *(float4*)(out + (size_t)((b0 + (T)*BT + bz) * Cc + cl) * Mm + m0 +      \
                 Qm * 4) = o;                                                  \
    }                                                                          \
  }

#define ITER(T)                                                                \
  {                                                                            \
    short8 Bf[2][2];                                                           \
    _Pragma("unroll") for (int mi = 0; mi < 2; ++mi)                           \
    _Pragma("unroll") for (int ks = 0; ks < 2; ++ks) Bf[mi][ks] =              \
        *(const short8*)(xl + ((w * 2 + mi) * 16 + (l & 15)) * 128 +           \
                         (((ks * 4 + (l >> 4)) ^ (l & 7)) << 4));              \
    f32x4 acc[2][4];                                                           \
    _Pragma("unroll") for (int mi = 0; mi < 2; ++mi)                           \
    _Pragma("unroll") for (int ct = 0; ct < 4; ++ct) acc[mi][ct] =             \
        (f32x4){0.f, 0.f, 0.f, 0.f};                                           \
    _Pragma("unroll") for (int ks = 0; ks < 2; ++ks)                           \
    _Pragma("unroll") for (int mi = 0; mi < 2; ++mi)                           \
    _Pragma("unroll") for (int ct = 0; ct < 4; ++ct) {                         \
      const float* sp = S + ((size_t)(m0 + w * 2 + mi) * Cc + ct * 16 +        \
                             (l & 15)) * Cc + ks * 32 + (l >> 4) * 8;          \
      const float4 f0 = *(const float4*)sp;                                    \
      const float4 f1v = *(const float4*)(sp + 4);                             \
      short8 a;                                                                \
      a[0] = bfc(f0.x); a[1] = bfc(f0.y); a[2] = bfc(f0.z); a[3] = bfc(f0.w);  \
      a[4] = bfc(f1v.x); a[5] = bfc(f1v.y); a[6] = bfc(f1v.z);                 \
      a[7] = bfc(f1v.w);                                                       \
      acc[mi][ct] = __builtin_amdgcn_mfma_f32_16x16x32_bf16(                   \
          a, Bf[mi][ks], acc[mi][ct], 0, 0, 0);                                \
    }                                                                          \
    ZW(0)                                                                      \
    BAR()                                                                      \
    ZR(0, T)                                                                   \
    if ((T) < NB - 1) { STAGE() }                                              \
    if ((T) < NB - 2) { ISSUE((T) + 2) }                                       \
    BAR()                                                                      \
    ZW(1)                                                                      \
    BAR()                                                                      \
    ZR(1, T)                                                                   \
    if ((T) < NB - 1) BAR()                                                    \
  }

  // prologue: stage tile 0, prefetch tile 1 into regs
  ISSUE(0)
  STAGE()
  ISSUE(1)
  BAR()

  ITER(0)
  ITER(1)
  ITER(2)
  ITER(3)

#undef ITER
#undef ZR
#undef ZW
#undef BAR
#undef STAGE
#undef ISSUE
}

extern "C" void kernel_launch(void* const* d_in, const int* in_sizes, int n_in,
                              void* d_out, int out_size, void* d_ws,
                              size_t ws_size, hipStream_t stream) {
  const float* x = (const float*)d_in[0];
  const float* mean = (const float*)d_in[1];
  const float* S = (const float*)d_in[2];
  float* out = (float*)d_out;
  float* Tt = (float*)d_ws;  // 64*512*4 = 128 KB
  hipLaunchKernelGGL(zca_prep, dim3(Mm), dim3(256), 0, stream, S, mean, Tt);
  const int nblocks = (Mm / MT) * (Bb / (BT * NB));  // 32 * 16 = 512
  hipLaunchKernelGGL(zca_v8, dim3(nblocks), dim3(512), 65536, stream, x, S, Tt,
                     out);
}